// Round 2
// baseline (1232.310 us; speedup 1.0000x reference)
//
#include <hip/hip_runtime.h>
#include <hip/hip_bf16.h>

// Problem: B=4, L=1024, C=768, H=12, D=64.  All inputs/outputs fp32.
// out0 = proj(attn(x));  out1 = attn_score [B,H,L,L].  d_out = [out0 | out1].
//
// Pipeline:
//   k1: qkv[4096][2304] (fp32, ws)  = x[4096][768] @ w_qkv[2304][768]^T
//   k2: per (b,h): sc = (q*scale) @ k^T ; softmax rows; write attn_score;
//       attn_ws[4096][768] (fp32)  = p @ v   (stored directly in [B,L,C] layout)
//   k3: out0[4096][768]            = attn_ws @ w_proj[768][768]^T + b_proj

#define BLK 256

// C[M][N] = A[M][K] @ B[N][K]^T (+ bias[N]).  64x64 tile, BK=16, 256 thr, 4x4 microtile.
template <bool BIAS>
__global__ __launch_bounds__(BLK) void gemm_bt_kernel(
    const float* __restrict__ A, const float* __restrict__ B,
    const float* __restrict__ bias, float* __restrict__ C,
    int M, int N, int K) {
  __shared__ float As[16][65];  // [k][m]
  __shared__ float Bs[16][65];  // [k][n]
  const int tx = threadIdx.x % 16;
  const int ty = threadIdx.x / 16;
  const int m0 = blockIdx.y * 64;
  const int n0 = blockIdx.x * 64;
  float acc[4][4] = {};
  for (int k0 = 0; k0 < K; k0 += 16) {
    for (int idx = threadIdx.x; idx < 1024; idx += BLK) {
      int mm = idx / 16, kk = idx % 16;
      As[kk][mm] = A[(size_t)(m0 + mm) * K + k0 + kk];
      Bs[kk][mm] = B[(size_t)(n0 + mm) * K + k0 + kk];
    }
    __syncthreads();
#pragma unroll
    for (int kk = 0; kk < 16; ++kk) {
      float a[4], b[4];
#pragma unroll
      for (int i = 0; i < 4; ++i) a[i] = As[kk][ty * 4 + i];
#pragma unroll
      for (int j = 0; j < 4; ++j) b[j] = Bs[kk][tx * 4 + j];
#pragma unroll
      for (int i = 0; i < 4; ++i)
#pragma unroll
        for (int j = 0; j < 4; ++j) acc[i][j] += a[i] * b[j];
    }
    __syncthreads();
  }
#pragma unroll
  for (int i = 0; i < 4; ++i) {
    int row = m0 + ty * 4 + i;
#pragma unroll
    for (int j = 0; j < 4; ++j) {
      int col = n0 + tx * 4 + j;
      float v = acc[i][j];
      if (BIAS) v += bias[col];
      C[(size_t)row * N + col] = v;
    }
  }
}

// Attention: grid (L/R, B*H), R=8 rows per block, 256 threads.
__global__ __launch_bounds__(BLK) void attn_kernel(
    const float* __restrict__ qkv, float* __restrict__ attn_out_ws,
    float* __restrict__ attn_score_out) {
  constexpr int L = 1024, H = 12, D = 64, C3 = 2304, R = 8;
  const int bh = blockIdx.y;
  const int b = bh / H, h = bh % H;
  const int l0 = blockIdx.x * R;
  const int tid = threadIdx.x;
  const float scale = 0.125f;  // 1/sqrt(64)

  __shared__ float qs[R][D];        // 2 KB
  __shared__ float sc[R][L];        // 32 KB
  __shared__ float kt[64][D + 1];   // 16.25 KB (k-tile / v-tile)

  const size_t base = (size_t)b * L * C3;

  // load Q rows, pre-scaled
  for (int idx = tid; idx < R * D; idx += BLK) {
    int r = idx / D, d = idx % D;
    qs[r][d] = qkv[base + (size_t)(l0 + r) * C3 + h * D + d] * scale;
  }

  // scores: sc[r][m] = qs[r][:] . k[m][:]
  for (int mt = 0; mt < L / 64; ++mt) {
    __syncthreads();
    for (int idx = tid; idx < 64 * D; idx += BLK) {
      int mm = idx / D, d = idx % D;
      kt[mm][d] = qkv[base + (size_t)(mt * 64 + mm) * C3 + 768 + h * D + d];
    }
    __syncthreads();
    int mm = tid % 64;
    int rg = tid / 64;  // 0..3
    for (int rr = rg; rr < R; rr += 4) {
      float acc = 0.f;
#pragma unroll
      for (int d = 0; d < D; ++d) acc += qs[rr][d] * kt[mm][d];
      sc[rr][mt * 64 + mm] = acc;
    }
  }
  __syncthreads();

  // softmax: 32 threads per row
  {
    int r = tid / 32, j = tid % 32;
    float mx = -1e30f;
    for (int m = j; m < L; m += 32) mx = fmaxf(mx, sc[r][m]);
#pragma unroll
    for (int off = 16; off; off >>= 1) mx = fmaxf(mx, __shfl_down(mx, off, 32));
    mx = __shfl(mx, 0, 32);
    float sum = 0.f;
    for (int m = j; m < L; m += 32) {
      float e = __expf(sc[r][m] - mx);
      sc[r][m] = e;
      sum += e;
    }
#pragma unroll
    for (int off = 16; off; off >>= 1) sum += __shfl_down(sum, off, 32);
    sum = __shfl(sum, 0, 32);
    float inv = 1.0f / sum;
    size_t obase = (size_t)bh * L * L + (size_t)l0 * L;
    for (int m = j; m < L; m += 32) {
      float p = sc[r][m] * inv;
      sc[r][m] = p;
      attn_score_out[obase + (size_t)r * L + m] = p;
    }
  }
  __syncthreads();

  // out = p @ v  (reuse kt as v-tile)
  int d = tid % 64;
  int r2 = tid / 64;  // rows r2 and r2+4
  float acc0 = 0.f, acc1 = 0.f;
  for (int mt = 0; mt < L / 64; ++mt) {
    __syncthreads();
    for (int idx = tid; idx < 64 * D; idx += BLK) {
      int mm = idx / D, dd = idx % D;
      kt[mm][dd] = qkv[base + (size_t)(mt * 64 + mm) * C3 + 1536 + h * D + dd];
    }
    __syncthreads();
#pragma unroll
    for (int mm = 0; mm < 64; ++mm) {
      float v = kt[mm][d];
      acc0 += sc[r2][mt * 64 + mm] * v;
      acc1 += sc[r2 + 4][mt * 64 + mm] * v;
    }
  }
  attn_out_ws[(size_t)(b * L + l0 + r2) * 768 + h * D + d] = acc0;
  attn_out_ws[(size_t)(b * L + l0 + r2 + 4) * 768 + h * D + d] = acc1;
}

extern "C" void kernel_launch(void* const* d_in, const int* in_sizes, int n_in,
                              void* d_out, int out_size, void* d_ws, size_t ws_size,
                              hipStream_t stream) {
  const float* x      = (const float*)d_in[0];  // [4,1024,768]
  const float* w_qkv  = (const float*)d_in[1];  // [2304,768]
  const float* w_proj = (const float*)d_in[2];  // [768,768]
  const float* b_proj = (const float*)d_in[3];  // [768]

  float* out0 = (float*)d_out;                          // [4096,768]
  float* out1 = out0 + (size_t)4096 * 768;              // [48,1024,1024]

  float* qkv_ws  = (float*)d_ws;                        // 4096*2304 f32 (37.75 MB)
  float* attn_ws = qkv_ws + (size_t)4096 * 2304;        // 4096*768  f32 (12.6 MB)

  // 1) qkv = x @ w_qkv^T
  {
    dim3 grid(2304 / 64, 4096 / 64), block(BLK);
    gemm_bt_kernel<false><<<grid, block, 0, stream>>>(x, w_qkv, nullptr, qkv_ws, 4096, 2304, 768);
  }
  // 2) attention
  {
    dim3 grid(1024 / 8, 4 * 12), block(BLK);
    attn_kernel<<<grid, block, 0, stream>>>(qkv_ws, attn_ws, out1);
  }
  // 3) out0 = attn_ws @ w_proj^T + b_proj
  {
    dim3 grid(768 / 64, 4096 / 64), block(BLK);
    gemm_bt_kernel<true><<<grid, block, 0, stream>>>(attn_ws, w_proj, b_proj, out0, 4096, 768, 768);
  }
}

// Round 3
// 379.533 us; speedup vs baseline: 3.2469x; 3.2469x over previous
//
#include <hip/hip_runtime.h>
#include <hip/hip_bf16.h>
#include <stdint.h>

// B=4, L=1024, C=768, H=12, D=64.  All inputs/outputs fp32.
// Pipeline (all-MFMA bf16, fp32 accumulate):
//   c1: cast x, w_qkv, w_proj -> bf16 ws
//   k1: qkv GEMM  [4096x768]@[2304x768]^T -> scatter q(pre*0.125),k [bh][l][d], v^T [bh][d][l]  (bf16)
//   k2: attention per (bh, 16 rows): QK^T MFMA -> bf16 S in LDS -> softmax -> out1 fp32 + PV MFMA -> attn_o bf16
//   k3: proj GEMM  [4096x768]@[768x768]^T + bias -> out0 fp32

typedef __attribute__((ext_vector_type(8))) short short8;
typedef __attribute__((ext_vector_type(4))) float floatx4;

#define MFMA16(A_, B_, C_) __builtin_amdgcn_mfma_f32_16x16x32_bf16((A_), (B_), (C_), 0, 0, 0)

__device__ __forceinline__ unsigned short f2bf(float f) {
  unsigned u = __builtin_bit_cast(unsigned, f);
  u += 0x7FFFu + ((u >> 16) & 1u);   // round-to-nearest-even
  return (unsigned short)(u >> 16);
}
__device__ __forceinline__ float bf2f(unsigned short u) {
  return __builtin_bit_cast(float, (unsigned)u << 16);
}

// ---------------- cast fp32 -> bf16 ----------------
__global__ __launch_bounds__(256) void cast_kernel(const float* __restrict__ src,
                                                   unsigned short* __restrict__ dst, int n) {
  int i = (blockIdx.x * 256 + threadIdx.x) * 4;
  if (i < n) {
    float4 v = *(const float4*)(src + i);
    ushort4 o;
    o.x = f2bf(v.x); o.y = f2bf(v.y); o.z = f2bf(v.z); o.w = f2bf(v.w);
    *(ushort4*)(dst + i) = o;
  }
}

// ---------------- bf16 MFMA GEMM: C[M][N] = A[M][K] @ Bm[N][K]^T ----------------
// tile 128x128, BK=32, 256 threads = 4 waves (wave (wm,wn) owns a 64x64 quadrant).
// EPI 0: qkv scatter epilogue.  EPI 1: fp32 C + bias epilogue.
template <int EPI>
__global__ __launch_bounds__(256) void gemm_bt(
    const unsigned short* __restrict__ A, const unsigned short* __restrict__ Bm,
    const float* __restrict__ bias,
    unsigned short* __restrict__ q_ws, unsigned short* __restrict__ k_ws,
    unsigned short* __restrict__ vt_ws, float* __restrict__ Cout,
    int M, int N, int K) {
  __shared__ __align__(16) unsigned short Al[128 * 32];
  __shared__ __align__(16) unsigned short Bl[128 * 32];
  const int tid = threadIdx.x;
  const int lane = tid & 63, wave = tid >> 6;
  const int q = lane >> 4, lm = lane & 15;
  const int wm = wave >> 1, wn = wave & 1;
  const int m0 = blockIdx.y * 128, n0 = blockIdx.x * 128;

  floatx4 acc[4][4];
#pragma unroll
  for (int i = 0; i < 4; ++i)
#pragma unroll
    for (int j = 0; j < 4; ++j) acc[i][j] = (floatx4){0.f, 0.f, 0.f, 0.f};

  for (int k0 = 0; k0 < K; k0 += 32) {
#pragma unroll
    for (int it = 0; it < 2; ++it) {
      int idx = tid + it * 256;  // 0..511 -> row = idx/4, 16B chunk = idx%4
      int row = idx >> 2, ch = idx & 3;
      const unsigned short* ga = A + (size_t)(m0 + row) * K + k0 + ch * 8;
      const unsigned short* gb = Bm + (size_t)(n0 + row) * K + k0 + ch * 8;
      __builtin_amdgcn_global_load_lds(
          (const __attribute__((address_space(1))) unsigned int*)ga,
          (__attribute__((address_space(3))) unsigned int*)(Al + idx * 8), 16, 0, 0);
      __builtin_amdgcn_global_load_lds(
          (const __attribute__((address_space(1))) unsigned int*)gb,
          (__attribute__((address_space(3))) unsigned int*)(Bl + idx * 8), 16, 0, 0);
    }
    __syncthreads();
    short8 af[4], bfr[4];
#pragma unroll
    for (int t = 0; t < 4; ++t) {
      af[t] = *(const short8*)(Al + (wm * 64 + t * 16 + lm) * 32 + q * 8);
      bfr[t] = *(const short8*)(Bl + (wn * 64 + t * 16 + lm) * 32 + q * 8);
    }
#pragma unroll
    for (int i = 0; i < 4; ++i)
#pragma unroll
      for (int j = 0; j < 4; ++j) acc[i][j] = MFMA16(af[i], bfr[j], acc[i][j]);
    __syncthreads();
  }

  if (EPI == 0) {
    // scatter to q_ws/k_ws [bh][l][64] and vt_ws [bh][64][1024], bf16
#pragma unroll
    for (int i = 0; i < 4; ++i) {
      int mb = m0 + wm * 64 + i * 16 + q * 4;
#pragma unroll
      for (int j = 0; j < 4; ++j) {
        int n = n0 + wn * 64 + j * 16 + lm;
        int which = n / 768;
        int r = n - which * 768;
        int h = r >> 6, d = r & 63;
#pragma unroll
        for (int rg = 0; rg < 4; ++rg) {
          int m = mb + rg;
          int b = m >> 10, l = m & 1023;
          float v = acc[i][j][rg];
          if (which == 0) v *= 0.125f;  // fold attention scale into q (exact in bf16)
          unsigned short bv = f2bf(v);
          if (which == 0)
            q_ws[(size_t)((b * 12 + h) * 1024 + l) * 64 + d] = bv;
          else if (which == 1)
            k_ws[(size_t)((b * 12 + h) * 1024 + l) * 64 + d] = bv;
          else
            vt_ws[(size_t)((b * 12 + h) * 64 + d) * 1024 + l] = bv;
        }
      }
    }
  } else {
#pragma unroll
    for (int i = 0; i < 4; ++i) {
      int mb = m0 + wm * 64 + i * 16 + q * 4;
#pragma unroll
      for (int j = 0; j < 4; ++j) {
        int n = n0 + wn * 64 + j * 16 + lm;
        float bv = bias[n];
#pragma unroll
        for (int rg = 0; rg < 4; ++rg) {
          int m = mb + rg;
          Cout[(size_t)m * N + n] = acc[i][j][rg] + bv;
        }
      }
    }
  }
}

// ---------------- attention ----------------
// grid (64, 48): 16 query rows per block, 256 threads = 4 waves.
__global__ __launch_bounds__(256) void attn_mfma(
    const unsigned short* __restrict__ q_ws, const unsigned short* __restrict__ k_ws,
    const unsigned short* __restrict__ vt_ws, unsigned short* __restrict__ attn_o,
    float* __restrict__ out1) {
  constexpr int L = 1024, SW = 1034;  // halfword stride: 16B-aligned rows, <=2-way banks on frag reads
  __shared__ __align__(16) unsigned short S[16 * SW];
  __shared__ float sinv[16];
  const int bh = blockIdx.y, b = bh / 12, h = bh % 12;
  const int l0 = blockIdx.x * 16;
  const int tid = threadIdx.x, lane = tid & 63, wave = tid >> 6;
  const int q = lane >> 4, lm = lane & 15;

  const size_t qk_base = (size_t)bh * L * 64;

  // Q fragments (A-layout: A[m=lane&15][k=quad*8+j]); q pre-scaled by 0.125
  const unsigned short* qr = q_ws + qk_base + (size_t)(l0 + lm) * 64;
  short8 aq0 = *(const short8*)(qr + q * 8);
  short8 aq1 = *(const short8*)(qr + 32 + q * 8);

  // ---- QK^T: wave owns column tiles [wave*16, wave*16+16) ----
#pragma unroll 2
  for (int ct = wave * 16; ct < wave * 16 + 16; ++ct) {
    const unsigned short* kr = k_ws + qk_base + (size_t)(ct * 16 + lm) * 64;
    short8 b0 = *(const short8*)(kr + q * 8);
    short8 b1 = *(const short8*)(kr + 32 + q * 8);
    floatx4 acc = (floatx4){0.f, 0.f, 0.f, 0.f};
    acc = MFMA16(aq0, b0, acc);
    acc = MFMA16(aq1, b1, acc);
#pragma unroll
    for (int rg = 0; rg < 4; ++rg)
      S[(q * 4 + rg) * SW + ct * 16 + lm] = f2bf(acc[rg]);  // C-layout: row=quad*4+reg, col=lane&15
  }
  __syncthreads();

  // ---- softmax: 16 threads per row (threads tid>>4 == row, contiguous 16-lane groups) ----
  {
    int r = tid >> 4, j = tid & 15;
    unsigned short* Sr = S + r * SW;
    float mx = -1e30f;
    for (int m = j; m < L; m += 16) mx = fmaxf(mx, bf2f(Sr[m]));
#pragma unroll
    for (int off = 1; off < 16; off <<= 1) mx = fmaxf(mx, __shfl_xor(mx, off, 16));
    float sum = 0.f;
    for (int m = j; m < L; m += 16) {
      float e = __expf(bf2f(Sr[m]) - mx);
      sum += e;
      Sr[m] = f2bf(e);  // store e; 1/sum folded in later
    }
#pragma unroll
    for (int off = 1; off < 16; off <<= 1) sum += __shfl_xor(sum, off, 16);
    if (j == 0) sinv[r] = 1.0f / sum;
  }
  __syncthreads();

  // ---- write attn_score (fp32, coalesced) ----
  {
    size_t ob = (size_t)bh * L * L + (size_t)l0 * L;
    for (int idx = tid; idx < 16 * L; idx += 256) {
      int r = idx >> 10, m = idx & (L - 1);
      out1[ob + (size_t)r * L + m] = bf2f(S[r * SW + m]) * sinv[r];
    }
  }

  // ---- PV: wave owns d-tile [wave*16, wave*16+16); K=1024 in 32 MFMA steps ----
  {
    floatx4 acc = (floatx4){0.f, 0.f, 0.f, 0.f};
    const unsigned short* vr = vt_ws + (size_t)(bh * 64 + wave * 16 + lm) * 1024;
#pragma unroll 4
    for (int ks = 0; ks < 32; ++ks) {
      const unsigned short* sp = S + lm * SW + ks * 32 + q * 8;
      union { unsigned u[4]; short8 s8; } af;
      af.u[0] = *(const unsigned*)(sp + 0);
      af.u[1] = *(const unsigned*)(sp + 2);
      af.u[2] = *(const unsigned*)(sp + 4);
      af.u[3] = *(const unsigned*)(sp + 6);
      short8 bv = *(const short8*)(vr + ks * 32 + q * 8);
      acc = MFMA16(af.s8, bv, acc);
    }
#pragma unroll
    for (int rg = 0; rg < 4; ++rg) {
      int row = q * 4 + rg;
      float v = acc[rg] * sinv[row];
      attn_o[(size_t)(b * 1024 + l0 + row) * 768 + h * 64 + wave * 16 + lm] = f2bf(v);
    }
  }
}

extern "C" void kernel_launch(void* const* d_in, const int* in_sizes, int n_in,
                              void* d_out, int out_size, void* d_ws, size_t ws_size,
                              hipStream_t stream) {
  const float* x      = (const float*)d_in[0];  // [4,1024,768]
  const float* w_qkv  = (const float*)d_in[1];  // [2304,768]
  const float* w_proj = (const float*)d_in[2];  // [768,768]
  const float* b_proj = (const float*)d_in[3];  // [768]

  float* out0 = (float*)d_out;                   // [4096,768]
  float* out1 = out0 + (size_t)4096 * 768;       // [48,1024,1024]

  const size_t NX = (size_t)4096 * 768;   // 3,145,728
  const size_t NWQ = (size_t)2304 * 768;  // 1,769,472
  const size_t NWP = (size_t)768 * 768;   //   589,824
  const size_t NQ = (size_t)48 * 1024 * 64;

  unsigned short* x_bf   = (unsigned short*)d_ws;
  unsigned short* wq_bf  = x_bf + NX;
  unsigned short* wp_bf  = wq_bf + NWQ;
  unsigned short* q_ws   = wp_bf + NWP;
  unsigned short* k_ws   = q_ws + NQ;
  unsigned short* vt_ws  = k_ws + NQ;
  unsigned short* attn_o = vt_ws + NQ;   // [4096][768] bf16

  // 1) casts
  cast_kernel<<<dim3(NX / 1024), dim3(256), 0, stream>>>(x, x_bf, (int)NX);
  cast_kernel<<<dim3(NWQ / 1024), dim3(256), 0, stream>>>(w_qkv, wq_bf, (int)NWQ);
  cast_kernel<<<dim3(NWP / 1024), dim3(256), 0, stream>>>(w_proj, wp_bf, (int)NWP);

  // 2) qkv GEMM + scatter
  gemm_bt<0><<<dim3(2304 / 128, 4096 / 128), dim3(256), 0, stream>>>(
      x_bf, wq_bf, nullptr, q_ws, k_ws, vt_ws, nullptr, 4096, 2304, 768);

  // 3) attention
  attn_mfma<<<dim3(64, 48), dim3(256), 0, stream>>>(q_ws, k_ws, vt_ws, attn_o, out1);

  // 4) proj GEMM + bias
  gemm_bt<1><<<dim3(768 / 128, 4096 / 128), dim3(256), 0, stream>>>(
      attn_o, wp_bf, b_proj, nullptr, nullptr, nullptr, out0, 4096, 768, 768);
}